// Round 5
// baseline (734.799 us; speedup 1.0000x reference)
//
#include <hip/hip_runtime.h>

#define BB 16
#define HW 4096
#define DIMC 256
#define NHEAD 8
#define CPH 8
#define NQKV 192
#define SCALE 0.17677669529663687f

typedef __attribute__((ext_vector_type(8))) short bf16x8;
typedef __attribute__((ext_vector_type(4))) float f32x4;

__device__ inline unsigned short f2b(float f) {
  union { float f; unsigned int u; } x; x.f = f;
  unsigned int r = x.u + 0x7FFFu + ((x.u >> 16) & 1u);
  return (unsigned short)(r >> 16);
}
__device__ inline float b2f(unsigned short u) {
  union { unsigned int u; float f; } x; x.u = ((unsigned int)u) << 16;
  return x.f;
}
__device__ inline void async_copy16(const void* g, void* l) {
  __builtin_amdgcn_global_load_lds((const __attribute__((address_space(1))) void*)g,
                                   (__attribute__((address_space(3))) void*)l, 16, 0, 0);
}

// ---------------- K0a: qkv_w -> bf16 A-fragment-swizzled ----------------
__global__ __launch_bounds__(256) void cast_qw(const float* __restrict__ qw,
                                               unsigned short* __restrict__ qwf) {
  int t = blockIdx.x * 256 + threadIdx.x;  // 6144
  int lane = t & 63;
  int cell = t >> 6;  // band*8 + c32
  int m = lane & 15, g = lane >> 4;
  int band = cell >> 3, c32 = cell & 7;
  int j = band * 16 + m;
  int k = c32 * 32 + g * 8;
  unsigned short pk[8];
#pragma unroll
  for (int i = 0; i < 8; ++i) pk[i] = f2b(qw[j * 256 + k + i]);
  *(uint4*)&qwf[(size_t)t * 8] = *(uint4*)pk;
}

// ---------------- K0b: proj_w (256,64) -> bf16 A-fragment-swizzled ----------------
__global__ __launch_bounds__(256) void cast_pw(const float* __restrict__ pw,
                                               unsigned short* __restrict__ pwf) {
  int t = blockIdx.x * 256 + threadIdx.x;  // 2048
  int lane = t & 63;
  int cell = t >> 6;  // band*2 + c32
  int m = lane & 15, g = lane >> 4;
  int band = cell >> 1, c32 = cell & 1;
  int d = band * 16 + m;
  int j = c32 * 32 + g * 8;
  unsigned short pk[8];
#pragma unroll
  for (int i = 0; i < 8; ++i) pk[i] = f2b(pw[d * 64 + j + i]);
  *(uint4*)&pwf[(size_t)t * 8] = *(uint4*)pk;
}

// ---------------- K1: fused qkv GEMM (fp32 x staged, in-LDS transpose, bf16 MFMA) ----------------
// C(192j x 128s) = qw(192x256) * x(256k x 4096s). x staged fp32 in k-major chunks of 64,
// B-frags built by transposed LDS reads + bf16 pack. 16B chunks XOR-swizzled (same f on
// write and read) so the column reads are 2-way only (free).
__global__ __launch_bounds__(256, 2) void qkv_fused(const float* __restrict__ x,
                                                    const unsigned short* __restrict__ qwf,
                                                    const float* __restrict__ qb,
                                                    unsigned short* __restrict__ qkvt) {
  __shared__ float Xs[2][64 * 128];  // ping-pong, 64 k-rows x 128 s (512B rows), 64KB
  const int b = blockIdx.y;
  const int s_blk = blockIdx.x * 128;
  const int tid = threadIdx.x;
  const int wave = tid >> 6, lane = tid & 63;
  const float* xb = x + (size_t)b * (DIMC * HW);

  const int rhalf = lane >> 5, cch = lane & 31;

#define STAGE(CK, BUF)                                                        \
  {                                                                           \
    _Pragma("unroll")                                                         \
    for (int ii = 0; ii < 8; ++ii) {                                          \
      int a = wave * 8 + ii;                                                  \
      int row = 2 * a + rhalf;                                                \
      int g3 = row >> 3;                                                      \
      int fsw = (g3 & 3) | ((g3 & 1) << 2);                                   \
      const float* src = xb + (size_t)((CK) * 64 + row) * HW + s_blk +        \
                         (size_t)((cch ^ fsw) & 31) * 4 - (cch & ~31) * 0;    \
      async_copy16(src + ((cch & 24) * 4), (char*)&Xs[BUF][0] + a * 1024);    \
    }                                                                         \
  }
  // NOTE on swizzle: chunk index c in 0..31; swizzled low-3 bits only:
  // src chunk = (c & 24) | ((c ^ fsw) & 7). The macro above encodes this:
  // ((cch ^ fsw) & 31)*4 covers low bits (fsw<8 so only low 3 bits differ) --
  // but to be exact we add the high part separately: (cch & 24)*4 floats.
  // ((cch ^ fsw) & 31) keeps bits 3,4 of cch only if fsw doesn't touch them (it doesn't: fsw<8).
  // So src float offset = ((cch & 24) | ((cch ^ fsw) & 7)) * 4. Simplify below.
#undef STAGE

  auto stage = [&](int ck, int buf) {
#pragma unroll
    for (int ii = 0; ii < 8; ++ii) {
      int a = wave * 8 + ii;
      int row = 2 * a + rhalf;
      int g3 = row >> 3;
      int fsw = (g3 & 3) | ((g3 & 1) << 2);
      int src_chunk = (cch & 24) | ((cch ^ fsw) & 7);
      const float* src = xb + (size_t)(ck * 64 + row) * HW + s_blk + src_chunk * 4;
      async_copy16(src, (char*)&Xs[buf][0] + a * 1024);
    }
  };

  f32x4 acc[3][8];
#pragma unroll
  for (int t = 0; t < 3; ++t)
#pragma unroll
    for (int st = 0; st < 8; ++st) acc[t][st] = (f32x4){0.f, 0.f, 0.f, 0.f};

  const int n = lane & 15, g = lane >> 4;

  stage(0, 0);
#pragma unroll
  for (int ck = 0; ck < 4; ++ck) {
    __syncthreads();
    if (ck < 3) stage(ck + 1, (ck + 1) & 1);
    const float* Xc = &Xs[ck & 1][0];
#pragma unroll
    for (int kk = 0; kk < 2; ++kk) {
      const int c32 = ck * 2 + kk;
      bf16x8 af[3];
#pragma unroll
      for (int t = 0; t < 3; ++t) {
        int band = wave * 3 + t;
        af[t] = *(const bf16x8*)(qwf + ((size_t)(band * 8 + c32) * 64 + lane) * 8);
      }
#pragma unroll
      for (int st = 0; st < 8; ++st) {
        const int s_loc = st * 16 + n;
        const int sc = s_loc >> 2, s3 = s_loc & 3;
        float tv[8];
#pragma unroll
        for (int i = 0; i < 8; ++i) {
          int k = kk * 32 + g * 8 + i;
          int g3 = k >> 3;
          int fsw = (g3 & 3) | ((g3 & 1) << 2);
          int lc = (sc & 24) | ((sc ^ fsw) & 7);
          tv[i] = Xc[k * 128 + lc * 4 + s3];
        }
        union { unsigned int u[4]; bf16x8 v; } pk;
#pragma unroll
        for (int i = 0; i < 4; ++i)
          pk.u[i] = (unsigned int)f2b(tv[2 * i]) | ((unsigned int)f2b(tv[2 * i + 1]) << 16);
#pragma unroll
        for (int t = 0; t < 3; ++t)
          acc[t][st] = __builtin_amdgcn_mfma_f32_16x16x32_bf16(af[t], pk.v, acc[t][st], 0, 0, 0);
      }
    }
  }

  unsigned short* ob = qkvt + (size_t)b * (NQKV * HW);
#pragma unroll
  for (int t = 0; t < 3; ++t) {
    int j0 = (wave * 3 + t) * 16 + g * 4;
#pragma unroll
    for (int st = 0; st < 8; ++st) {
      int s = s_blk + st * 16 + n;
#pragma unroll
      for (int r = 0; r < 4; ++r) {
        float v = acc[t][st][r] + qb[j0 + r];
        ob[(size_t)(j0 + r) * HW + s] = f2b(v);
      }
    }
  }
}

// ---------------- K2 v4: thread-owns-everything fused attn ----------------
// Block = one (b,n) x 32x32 tile, 256 threads. Thread owns a vertical 4-px strip
// and computes ALL 8 channels (coeffs re-read per c as wave-uniform LDS broadcast).
// No cross-wave reduction; logits/softmax/out in registers. kk->vv halo restage.
__global__ __launch_bounds__(256, 3) void attn_kernel(const unsigned short* __restrict__ qkvt,
                                                      const float* __restrict__ dcb,
                                                      const float* __restrict__ w1,
                                                      const float* __restrict__ dc1b,
                                                      const float* __restrict__ rpb,
                                                      unsigned short* __restrict__ aoT) {
  __shared__ float hal[8][34][36];   // one halo set (kk then vv), 39.2KB
  __shared__ float wAc[8][128];      // A (9 rows pad 12, diag+1 folded) + dK@108 + dV@117

  const int bn = blockIdx.x;   // b*8+n
  const int tile = blockIdx.y; // 0..3
  const int b = bn >> 3, n = bn & 7;
  const int h0 = (tile >> 1) * 32, w0 = (tile & 1) * 32;
  const int tid = threadIdx.x;
  const int col = tid & 31, rg = tid >> 5;
  const int R = rg * 4;  // strip rows R..R+3 (tile-relative)
  const unsigned short* fb = qkvt + ((size_t)b * NQKV + n * 24) * HW;

  // ---- stage coefficients (once) ----
  for (int e = tid; e < 648; e += 256) {
    int c = e / 81, idx = e - c * 81;
    int p = idx / 9, rs = idx - p * 9;
    wAc[c][p * 12 + rs] = w1[e] + (p == rs ? 1.f : 0.f);
  }
  if (tid < 72) {
    int c = tid / 9, p = tid - c * 9;
    float base = dcb[tid] + dc1b[tid];
    wAc[c][108 + p] = base + rpb[n * 9 + p];
    wAc[c][117 + p] = base;
  }
  // ---- stage kk halos: 8 bufs x 34 x 34 ----
  for (int e = tid; e < 9248; e += 256) {
    int cb = e / 1156;
    int r2 = e - cb * 1156;
    int hy = r2 / 34, hx = r2 - hy * 34;
    int gy = h0 - 1 + hy, gx = w0 - 1 + hx;
    float v = 0.f;
    if ((unsigned)gy < 64u && (unsigned)gx < 64u)
      v = b2f(fb[(size_t)(8 + cb) * HW + gy * 64 + gx]);
    hal[cb][hy][hx] = v;
  }
  __syncthreads();

  float logit[9][4];
#pragma unroll
  for (int p = 0; p < 9; ++p)
#pragma unroll
    for (int i = 0; i < 4; ++i) logit[p][i] = 0.f;

  // ---- K phase: loop channels; taps 6 rows x 3 cols shared by the 4-px strip ----
  float qn[4];
#pragma unroll
  for (int i = 0; i < 4; ++i)
    qn[i] = SCALE * b2f(fb[(size_t)0 * HW + (h0 + R + i) * 64 + (w0 + col)]);
#pragma unroll
  for (int c = 0; c < 8; ++c) {
    float qv[4];
#pragma unroll
    for (int i = 0; i < 4; ++i) qv[i] = qn[i];
    if (c < 7) {
#pragma unroll
      for (int i = 0; i < 4; ++i)
        qn[i] = SCALE * b2f(fb[(size_t)(c + 1) * HW + (h0 + R + i) * 64 + (w0 + col)]);
    }
    float T[6][3];
#pragma unroll
    for (int r6 = 0; r6 < 6; ++r6)
#pragma unroll
      for (int dx = 0; dx < 3; ++dx) T[r6][dx] = hal[c][R + r6][col + dx];
#pragma unroll
    for (int p = 0; p < 9; ++p) {
      float4 a0 = *(const float4*)&wAc[c][p * 12];
      float4 a1 = *(const float4*)&wAc[c][p * 12 + 4];
      float a8 = wAc[c][p * 12 + 8];
      float A9[9] = {a0.x, a0.y, a0.z, a0.w, a1.x, a1.y, a1.z, a1.w, a8};
      float dk = wAc[c][108 + p];
      float kv[4] = {dk, dk, dk, dk};
#pragma unroll
      for (int ry = 0; ry < 3; ++ry)
#pragma unroll
        for (int rx = 0; rx < 3; ++rx)
#pragma unroll
          for (int i = 0; i < 4; ++i)
            kv[i] = fmaf(A9[ry * 3 + rx], T[i + ry][rx], kv[i]);
#pragma unroll
      for (int i = 0; i < 4; ++i) logit[p][i] = fmaf(qv[i], kv[i], logit[p][i]);
    }
  }
  __syncthreads();  // all kk reads done

  // ---- restage vv halos into same buffer ----
  for (int e = tid; e < 9248; e += 256) {
    int cb = e / 1156;
    int r2 = e - cb * 1156;
    int hy = r2 / 34, hx = r2 - hy * 34;
    int gy = h0 - 1 + hy, gx = w0 - 1 + hx;
    float v = 0.f;
    if ((unsigned)gy < 64u && (unsigned)gx < 64u)
      v = b2f(fb[(size_t)(16 + cb) * HW + gy * 64 + gx]);
    hal[cb][hy][hx] = v;
  }

  // ---- softmax (registers only; overlaps staging latency) ----
#pragma unroll
  for (int i = 0; i < 4; ++i) {
    float m = logit[0][i];
#pragma unroll
    for (int p = 1; p < 9; ++p) m = fmaxf(m, logit[p][i]);
    float den = 0.f;
#pragma unroll
    for (int p = 0; p < 9; ++p) {
      float e = __expf(logit[p][i] - m);
      logit[p][i] = e;
      den += e;
    }
    float inv = 1.f / den;
#pragma unroll
    for (int p = 0; p < 9; ++p) logit[p][i] *= inv;
  }
  __syncthreads();  // vv staged

  // ---- V phase ----
  float outc[8][4];
#pragma unroll
  for (int c = 0; c < 8; ++c)
#pragma unroll
    for (int i = 0; i < 4; ++i) outc[c][i] = 0.f;
#pragma unroll
  for (int c = 0; c < 8; ++c) {
    float T[6][3];
#pragma unroll
    for (int r6 = 0; r6 < 6; ++r6)
#pragma unroll
      for (int dx = 0; dx < 3; ++dx) T[r6][dx] = hal[c][R + r6][col + dx];
#pragma unroll
    for (int p = 0; p < 9; ++p) {
      float4 a0 = *(const float4*)&wAc[c][p * 12];
      float4 a1 = *(const float4*)&wAc[c][p * 12 + 4];
      float a8 = wAc[c][p * 12 + 8];
      float A9[9] = {a0.x, a0.y, a0.z, a0.w, a1.x, a1.y, a1.z, a1.w, a8};
      float dv = wAc[c][117 + p];
      float vv[4] = {dv, dv, dv, dv};
#pragma unroll
      for (int ry = 0; ry < 3; ++ry)
#pragma unroll
        for (int rx = 0; rx < 3; ++rx)
#pragma unroll
          for (int i = 0; i < 4; ++i)
            vv[i] = fmaf(A9[ry * 3 + rx], T[i + ry][rx], vv[i]);
#pragma unroll
      for (int i = 0; i < 4; ++i) outc[c][i] = fmaf(logit[p][i], vv[i], outc[c][i]);
    }
  }

  // ---- write aoT[b][s][n*8 + 0..7]: one 16B store per pixel ----
#pragma unroll
  for (int i = 0; i < 4; ++i) {
    int s = (h0 + R + i) * 64 + (w0 + col);
    uint4 val;
    val.x = (unsigned int)f2b(outc[0][i]) | ((unsigned int)f2b(outc[1][i]) << 16);
    val.y = (unsigned int)f2b(outc[2][i]) | ((unsigned int)f2b(outc[3][i]) << 16);
    val.z = (unsigned int)f2b(outc[4][i]) | ((unsigned int)f2b(outc[5][i]) << 16);
    val.w = (unsigned int)f2b(outc[6][i]) | ((unsigned int)f2b(outc[7][i]) << 16);
    *(uint4*)&aoT[((size_t)b * HW + s) * 64 + n * 8] = val;
  }
}

// ---------------- K3: proj GEMM via bf16 MFMA ----------------
__global__ __launch_bounds__(256) void proj_mfma(const unsigned short* __restrict__ aoT,
                                                 const unsigned short* __restrict__ pwf,
                                                 const float* __restrict__ pb,
                                                 float* __restrict__ out) {
  __shared__ unsigned short Bs[128 * 64];
  const int b = blockIdx.y;
  const int s_blk = blockIdx.x * 128;
  const int tid = threadIdx.x;
  const int wave = tid >> 6, lane = tid & 63;

  {
    const int slot = lane & 7, rsub = lane >> 3;
#pragma unroll
    for (int ii = 0; ii < 4; ++ii) {
      int i = wave * 4 + ii;
      int row = 8 * i + rsub;
      int mem_chunk = slot ^ rsub;
      const unsigned short* src =
          aoT + ((size_t)b * HW + s_blk + row) * 64 + mem_chunk * 8;
      async_copy16(src, (char*)Bs + i * 1024);
    }
  }
  __syncthreads();

  f32x4 acc[4][8];
#pragma unroll
  for (int t = 0; t < 4; ++t)
#pragma unroll
    for (int st = 0; st < 8; ++st) acc[t][st] = (f32x4){0.f, 0.f, 0.f, 0.f};

  const int n = lane & 15, g = lane >> 4;
#pragma unroll
  for (int c32 = 0; c32 < 2; ++c32) {
    bf16x8 af[4];
#pragma unroll
    for (int t = 0; t < 4; ++t) {
      int band = wave * 4 + t;
      af[t] = *(const bf16x8*)(pwf + ((size_t)(band * 2 + c32) * 64 + lane) * 8);
    }
#pragma unroll
    for (int st = 0; st < 8; ++st) {
      int s_row = st * 16 + n;
      int mc = c32 * 4 + g;
      int stc = mc ^ (s_row & 7);
      bf16x8 bf = *(const bf16x8*)&Bs[s_row * 64 + stc * 8];
#pragma unroll
      for (int t = 0; t < 4; ++t)
        acc[t][st] = __builtin_amdgcn_mfma_f32_16x16x32_bf16(af[t], bf, acc[t][st], 0, 0, 0);
    }
  }

  float bias[4][4];
#pragma unroll
  for (int t = 0; t < 4; ++t)
#pragma unroll
    for (int r = 0; r < 4; ++r) bias[t][r] = pb[(wave * 4 + t) * 16 + g * 4 + r];

  float* ob = out + ((size_t)b << 20);
#pragma unroll
  for (int t = 0; t < 4; ++t) {
    int d0 = (wave * 4 + t) * 16 + g * 4;
#pragma unroll
    for (int st = 0; st < 8; ++st) {
      int s = s_blk + st * 16 + n;
#pragma unroll
      for (int r = 0; r < 4; ++r)
        ob[(size_t)(d0 + r) * HW + s] = acc[t][st][r] + bias[t][r];
    }
  }
}

extern "C" void kernel_launch(void* const* d_in, const int* in_sizes, int n_in,
                              void* d_out, int out_size, void* d_ws, size_t ws_size,
                              hipStream_t stream) {
  (void)in_sizes; (void)n_in; (void)out_size; (void)ws_size;
  const float* x    = (const float*)d_in[0];
  const float* qw   = (const float*)d_in[5];
  const float* qb   = (const float*)d_in[6];
  const float* dcb  = (const float*)d_in[7];
  const float* w1   = (const float*)d_in[8];
  const float* dc1b = (const float*)d_in[9];
  const float* rpb  = (const float*)d_in[10];
  const float* pw   = (const float*)d_in[11];
  const float* pb   = (const float*)d_in[12];

  // Workspace (time-multiplexed):
  // [0, 25165824)            qkvt bf16 (B,192,4096)           qkv -> attn
  // [25165824, 33554432)     qwf (cast_qw -> qkv, dead after) THEN aoT bf16 (attn -> proj)
  // [33554432, 33556480)     pwf (cast_pw -> proj)
  unsigned short* qkvt = (unsigned short*)d_ws;
  unsigned short* qwf  = (unsigned short*)((char*)d_ws + 25165824);
  unsigned short* aoT  = (unsigned short*)((char*)d_ws + 25165824);
  unsigned short* pwf  = (unsigned short*)((char*)d_ws + 33554432);

  cast_qw<<<24, 256, 0, stream>>>(qw, qwf);
  cast_pw<<<8, 256, 0, stream>>>(pw, pwf);
  qkv_fused<<<dim3(32, BB), 256, 0, stream>>>(x, qwf, qb, qkvt);
  attn_kernel<<<dim3(BB * NHEAD, 4), 256, 0, stream>>>(qkvt, dcb, w1, dc1b, rpb, aoT);
  proj_mfma<<<dim3(32, BB), 256, 0, stream>>>(aoT, pwf, pb, (float*)d_out);
}